// Round 7
// baseline (227.728 us; speedup 1.0000x reference)
//
#include <hip/hip_runtime.h>

#define NT   256
#define HW   3136          // 56*56 = 64 lanes * 49 elements
#define KSEL 627u          // int(0.2 * 3136)
#define CAP  512           // candidate list capacity
#define T1B  0x3F933333u   // ~1.15f  (seed bracket lo)
#define T2B  0x3FB9999Au   // ~1.45f  (seed bracket hi)

typedef unsigned int u32;
typedef unsigned long long u64;

__device__ __forceinline__ u32 prefix_cnt(u64 m) {   // #set bits below this lane
    return __builtin_amdgcn_mbcnt_hi((u32)(m >> 32),
           __builtin_amdgcn_mbcnt_lo((u32)m, 0u));
}

__global__ __launch_bounds__(NT, 8) void topk_mask_kernel(const float* __restrict__ x,
                                                          float* __restrict__ out) {
    __shared__ u32 LkA[4][CAP];   // per-wave candidate keys (|x| bits)
    __shared__ u32 LiA[4][CAP];   // per-wave candidate indices

    const int tid  = threadIdx.x;
    const int wid  = tid >> 6;
    const int lane = tid & 63;
    const u32 row  = blockIdx.x * 4u + (u32)wid;

    const float* xrow = x + (size_t)row * HW;
    const uint4* xr   = (const uint4*)xrow;
    float*       orow = out + (size_t)row * HW;
    uint4*       orwu = (uint4*)orow;

    u32* Lk = LkA[wid];
    u32* Li = LiA[wid];

    const float t1 = __uint_as_float(T1B);
    const float t2 = __uint_as_float(T2B);

    // ---- Pass A: streaming seed scan (counts at T1,T2) + compaction of [T1,T2)
    //      Row is NOT retained in registers (VGPR <= 64 for 8 waves/SIMD).
    u32 c1 = 0, c2 = 0, base = 0;
#define PROCA(F, IDX)                                                          \
    { const float _f = (F);                                                    \
      const u64 m1 = __ballot(__builtin_fabsf(_f) >= t1);                      \
      const u64 m2 = __ballot(__builtin_fabsf(_f) >= t2);                      \
      c1 += (u32)__popcll(m1); c2 += (u32)__popcll(m2);                        \
      const u64 mb = m1 & ~m2;                                                 \
      if ((mb >> lane) & 1ull) {                                               \
          const u32 off = base + prefix_cnt(mb);                               \
          Lk[off] = __float_as_uint(_f) & 0x7fffffffu; Li[off] = (IDX); }      \
      base += (u32)__popcll(mb); }
#pragma unroll
    for (int j = 0; j < 12; ++j) {
        const uint4 a = xr[lane + (j << 6)];
        const u32 bi = (u32)(lane << 2) + (u32)(j << 8);
        PROCA(__uint_as_float(a.x), bi + 0u)
        PROCA(__uint_as_float(a.y), bi + 1u)
        PROCA(__uint_as_float(a.z), bi + 2u)
        PROCA(__uint_as_float(a.w), bi + 3u)
    }
    const float tvf = xrow[3072 + lane];
    PROCA(tvf, 3072u + (u32)lane)
#undef PROCA

    // ---- establish bracket [lo,hi) with cnt(>=lo) >= k > cnt(>=hi), active <= CAP
    u32 lo, hi, clo, chi, active;
    const bool seeded = (c1 >= KSEL) && (KSEL > c2) && ((c1 - c2) <= CAP);
    if (seeded) {
        lo = T1B; hi = T2B; clo = c1; chi = c2; active = c1 - c2;
    } else {
        // rare general path: midpoint bisection in key space, reload row per probe (L2-hot)
        lo = 0u; clo = HW; hi = 0x80000000u; chi = 0u;
        if (c1 >= KSEL) {
            lo = T1B; clo = c1;
            if (c2 >= KSEL) { lo = T2B; clo = c2; }
            else            { hi = T2B; chi = c2; }
        } else { hi = T1B; chi = c1; }
        while (clo - chi > CAP && hi - lo > 1u) {
            const u32 mid = lo + ((hi - lo) >> 1);
            const float mf = __uint_as_float(mid);   // mid < 0x80000000
            u32 c = 0;
            for (int j = 0; j < 12; ++j) {
                const uint4 a = xr[lane + (j << 6)];
                c += (u32)__popcll(__ballot(__builtin_fabsf(__uint_as_float(a.x)) >= mf));
                c += (u32)__popcll(__ballot(__builtin_fabsf(__uint_as_float(a.y)) >= mf));
                c += (u32)__popcll(__ballot(__builtin_fabsf(__uint_as_float(a.z)) >= mf));
                c += (u32)__popcll(__ballot(__builtin_fabsf(__uint_as_float(a.w)) >= mf));
            }
            c += (u32)__popcll(__ballot(__builtin_fabsf(xrow[3072 + lane]) >= mf));
            if (c >= KSEL) { lo = mid; clo = c; } else { hi = mid; chi = c; }
        }
        active = clo - chi;
        if (active <= CAP) {   // recompact with final bracket (exact int compares)
            base = 0;
#define PROCB(F, IDX)                                                          \
            { const u32 _k = __float_as_uint(F) & 0x7fffffffu;                 \
              const u64 mb = __ballot(_k >= lo && _k < hi);                    \
              if ((mb >> lane) & 1ull) {                                       \
                  const u32 off = base + prefix_cnt(mb);                       \
                  Lk[off] = _k; Li[off] = (IDX); }                             \
              base += (u32)__popcll(mb); }
            for (int j = 0; j < 12; ++j) {
                const uint4 a = xr[lane + (j << 6)];
                const u32 bi = (u32)(lane << 2) + (u32)(j << 8);
                PROCB(__uint_as_float(a.x), bi + 0u)
                PROCB(__uint_as_float(a.y), bi + 1u)
                PROCB(__uint_as_float(a.z), bi + 2u)
                PROCB(__uint_as_float(a.w), bi + 3u)
            }
            PROCB(tvf, 3072u + (u32)lane)
#undef PROCB
        }
    }

    u32 TK, CO = HW - 1u;
    if (active > CAP) {
        // ---- degenerate: hi-lo==1 with >CAP duplicates of key 'lo' (never on real data)
        TK = lo;
        const u32 rk = KSEL - chi;
        u32 lo3 = 0u, hi3 = HW - 1u;
        while (lo3 < hi3) {
            const u32 mid = (lo3 + hi3) >> 1;
            u32 c = 0;
            for (int j = 0; j < 12; ++j) {
                const uint4 a = xr[lane + (j << 6)];
                const u32 bi = (u32)(lane << 2) + (u32)(j << 8);
                c += (u32)__popcll(__ballot(((a.x & 0x7fffffffu) == TK) && (bi + 0u) <= mid));
                c += (u32)__popcll(__ballot(((a.y & 0x7fffffffu) == TK) && (bi + 1u) <= mid));
                c += (u32)__popcll(__ballot(((a.z & 0x7fffffffu) == TK) && (bi + 2u) <= mid));
                c += (u32)__popcll(__ballot(((a.w & 0x7fffffffu) == TK) && (bi + 3u) <= mid));
            }
            c += (u32)__popcll(__ballot(((__float_as_uint(tvf) & 0x7fffffffu) == TK) && (3072u + (u32)lane) <= mid));
            if (c >= rk) hi3 = mid; else lo3 = mid + 1u;
        }
        CO = lo3;
    } else {
        // ---- finisher on compacted candidates (int-exact, wave-local, no barriers)
        const u32 Lc = active;
        const u32 rk = KSEL - chi;       // 1 <= rk <= Lc
        u32 ek[8];
#pragma unroll
        for (int j2 = 0; j2 < 8; ++j2) {
            const u32 s = (u32)lane + (u32)(j2 << 6);
            const u32 kk = Lk[s];        // always in-bounds (CAP = 512)
            ek[j2] = (s < Lc) ? kk : 0u; // pad 0: never >= any probe, never > / == TK
        }
        u32 lo2 = lo, hi2 = hi;
        bool done = false;
        while (hi2 - lo2 > 1u) {
            const u32 mid = lo2 + ((hi2 - lo2) >> 1);
            u32 c = 0;
#pragma unroll
            for (int j2 = 0; j2 < 8; ++j2)
                c += (u32)__popcll(__ballot(ek[j2] >= mid));
            if (c == rk) {
                // exact hit: threshold = min candidate >= mid; keep-set = all of them
                u32 mn = 0xffffffffu;
#pragma unroll
                for (int j2 = 0; j2 < 8; ++j2) {
                    const u32 kk = (ek[j2] >= mid) ? ek[j2] : 0xffffffffu;
                    mn = mn < kk ? mn : kk;
                }
#pragma unroll
                for (int o = 32; o >= 1; o >>= 1) {
                    const u32 t = (u32)__shfl_xor((int)mn, o, 64);
                    mn = mn < t ? mn : t;
                }
                TK = mn; done = true; break;
            }
            if (c > rk) lo2 = mid; else hi2 = mid;
        }
        if (!done) {
            TK = lo2;
            u32 cgt = 0;
#pragma unroll
            for (int j2 = 0; j2 < 8; ++j2)
                cgt += (u32)__popcll(__ballot(ek[j2] > TK));
            const u32 r = rk - cgt;      // equals to keep, >= 1
            u32 eqs = 0;
#pragma unroll
            for (int j2 = 0; j2 < 8; ++j2)
                eqs += (u32)__popcll(__ballot(ek[j2] == TK));
            if (r != eqs) {
                // cold tie path: r-th smallest index among equals (all are in the list)
                u64 eqm[8]; u32 ei[8];
#pragma unroll
                for (int j2 = 0; j2 < 8; ++j2) {
                    const u32 s = (u32)lane + (u32)(j2 << 6);
                    eqm[j2] = __ballot(ek[j2] == TK);
                    ei[j2]  = Li[s];
                }
                u32 lo3 = 0u, hi3 = HW - 1u;
                while (lo3 < hi3) {
                    const u32 mid = (lo3 + hi3) >> 1;
                    u32 c = 0;
#pragma unroll
                    for (int j2 = 0; j2 < 8; ++j2)
                        c += (u32)__popcll(eqm[j2] & __ballot(ei[j2] <= mid));
                    if (c >= r) hi3 = mid; else lo3 = mid + 1u;
                }
                CO = lo3;
            }
        }
    }

    // ---- Pass B: reload row (L2-hot) and mask. Stores are uint4 (bit-identical).
    if (CO == HW - 1u) {
        const float tkf = __uint_as_float(TK);   // finite; float cmp == int-key cmp
#pragma unroll
        for (int j = 0; j < 12; ++j) {
            const uint4 a = xr[lane + (j << 6)];
            uint4 o;
            o.x = (__builtin_fabsf(__uint_as_float(a.x)) >= tkf) ? a.x : 0u;
            o.y = (__builtin_fabsf(__uint_as_float(a.y)) >= tkf) ? a.y : 0u;
            o.z = (__builtin_fabsf(__uint_as_float(a.z)) >= tkf) ? a.z : 0u;
            o.w = (__builtin_fabsf(__uint_as_float(a.w)) >= tkf) ? a.w : 0u;
            orwu[lane + (j << 6)] = o;
        }
        orow[3072 + lane] = (__builtin_fabsf(tvf) >= tkf) ? tvf : 0.0f;
    } else {
        // cold tie path: exact int compares with index cutoff
#define KEEPU(U, IDX) ((((U) & 0x7fffffffu) > TK ||                            \
                        (((U) & 0x7fffffffu) == TK && (IDX) <= CO)) ? (U) : 0u)
        for (int j = 0; j < 12; ++j) {
            const uint4 a = xr[lane + (j << 6)];
            const u32 bi = (u32)(lane << 2) + (u32)(j << 8);
            uint4 o;
            o.x = KEEPU(a.x, bi + 0u);
            o.y = KEEPU(a.y, bi + 1u);
            o.z = KEEPU(a.z, bi + 2u);
            o.w = KEEPU(a.w, bi + 3u);
            orwu[lane + (j << 6)] = o;
        }
        orow[3072 + lane] = __uint_as_float(KEEPU(__float_as_uint(tvf), 3072u + (u32)lane));
#undef KEEPU
    }
}

extern "C" void kernel_launch(void* const* d_in, const int* in_sizes, int n_in,
                              void* d_out, int out_size, void* d_ws, size_t ws_size,
                              hipStream_t stream) {
    const float* x = (const float*)d_in[0];
    float* out = (float*)d_out;
    const int rows = in_sizes[0] / HW;       // 8192
    topk_mask_kernel<<<rows / 4, NT, 0, stream>>>(x, out);
}

// Round 8
// 219.280 us; speedup vs baseline: 1.0385x; 1.0385x over previous
//
#include <hip/hip_runtime.h>

#define NT   256
#define HW   3136          // 56*56 = 64 lanes * 49 elements
#define KSEL 627u          // int(0.2 * 3136)
#define CAP  512           // candidate list capacity
#define T1B  0x3F933333u   // ~1.15f bits (seed bracket lo)
#define T2B  0x3FB9999Au   // ~1.45f bits (seed bracket hi)

typedef unsigned int u32;
typedef unsigned long long u64;

__device__ __forceinline__ u32 prefix_cnt(u64 m) {   // #set bits below this lane
    return __builtin_amdgcn_mbcnt_hi((u32)(m >> 32),
           __builtin_amdgcn_mbcnt_lo((u32)m, 0u));
}

__global__ __launch_bounds__(NT, 8) void topk_mask_kernel(const float* __restrict__ x,
                                                          float* __restrict__ out) {
    __shared__ u32 LkA[4][CAP];   // per-wave: full value bits of band candidates
    __shared__ u32 LiA[4][CAP];   // per-wave: their spatial indices

    const int tid  = threadIdx.x;
    const int wid  = tid >> 6;
    const int lane = tid & 63;
    const u32 row  = blockIdx.x * 4u + (u32)wid;

    const float* xrow = x + (size_t)row * HW;
    const uint4* xr   = (const uint4*)xrow;
    float*       orow = out + (size_t)row * HW;
    uint4*       orwu = (uint4*)orow;

    u32* Lk = LkA[wid];
    u32* Li = LiA[wid];

    // ---- Pass A: single streaming pass.
    //  out[i] = x[i] if |x|>=T2 (definitely kept), else 0 (provisional for band).
    //  Band elements [T1,T2) compacted to LDS with full bits + index.
    u32 c1 = 0, c2 = 0, base = 0;
#define PROCA(U, IDX, OCOMP)                                                   \
    { const u32 _k = (U) & 0x7fffffffu;                                        \
      const u64 m1 = __ballot(_k >= T1B);                                      \
      const u64 m2 = __ballot(_k >= T2B);                                      \
      c1 += (u32)__popcll(m1); c2 += (u32)__popcll(m2);                        \
      OCOMP = (_k >= T2B) ? (U) : 0u;                                          \
      const u64 mb = m1 & ~m2;                                                 \
      if ((mb >> lane) & 1ull) {                                               \
          const u32 off = base + prefix_cnt(mb);                               \
          Lk[off] = (U); Li[off] = (IDX); }                                    \
      base += (u32)__popcll(mb); }
#pragma unroll
    for (int j = 0; j < 12; ++j) {
        const uint4 a = xr[lane + (j << 6)];
        const u32 bi = (u32)(lane << 2) + (u32)(j << 8);
        uint4 o;
        PROCA(a.x, bi + 0u, o.x)
        PROCA(a.y, bi + 1u, o.y)
        PROCA(a.z, bi + 2u, o.z)
        PROCA(a.w, bi + 3u, o.w)
        orwu[lane + (j << 6)] = o;
    }
    const u32 tvu = __float_as_uint(xrow[3072 + lane]);
    {
        u32 ot;
        PROCA(tvu, 3072u + (u32)lane, ot)
        orow[3072 + lane] = __uint_as_float(ot);
    }
#undef PROCA

    // ---- bracket [lo,hi): cnt(>=lo) >= k > cnt(>=hi), list holds keys in [lo,hi)
    u32 lo, hi, chi, Lc;
    bool fullrw = false, degen = false;
    if ((c1 >= KSEL) && (KSEL > c2) && ((c1 - c2) <= CAP)) {
        lo = T1B; hi = T2B; chi = c2; Lc = c1 - c2;          // list already valid
    } else {
        // rare general path: key-space bisection with row reloads (correctness only)
        fullrw = true;
        u32 clo;
        lo = 0u; clo = HW; hi = 0x80000000u; chi = 0u;
        if (c1 >= KSEL) {
            lo = T1B; clo = c1;
            if (c2 >= KSEL) { lo = T2B; clo = c2; }
            else            { hi = T2B; chi = c2; }
        } else { hi = T1B; chi = c1; }
        while (clo - chi > CAP && hi - lo > 1u) {
            const u32 mid = lo + ((hi - lo) >> 1);
            u32 c = 0;
#pragma unroll 1
            for (int j = 0; j < 12; ++j) {
                const uint4 a = xr[lane + (j << 6)];
                c += (u32)__popcll(__ballot((a.x & 0x7fffffffu) >= mid));
                c += (u32)__popcll(__ballot((a.y & 0x7fffffffu) >= mid));
                c += (u32)__popcll(__ballot((a.z & 0x7fffffffu) >= mid));
                c += (u32)__popcll(__ballot((a.w & 0x7fffffffu) >= mid));
            }
            c += (u32)__popcll(__ballot((tvu & 0x7fffffffu) >= mid));
            if (c >= KSEL) { lo = mid; clo = c; } else { hi = mid; chi = c; }
        }
        Lc = clo - chi;
        if (Lc <= CAP) {   // recompact list with final bracket
            base = 0;
#define PROCB(U, IDX)                                                          \
            { const u32 _k = (U) & 0x7fffffffu;                                \
              const u64 mb = __ballot(_k >= lo && _k < hi);                    \
              if ((mb >> lane) & 1ull) {                                       \
                  const u32 off = base + prefix_cnt(mb);                       \
                  Lk[off] = (U); Li[off] = (IDX); }                            \
              base += (u32)__popcll(mb); }
#pragma unroll 1
            for (int j = 0; j < 12; ++j) {
                const uint4 a = xr[lane + (j << 6)];
                const u32 bi = (u32)(lane << 2) + (u32)(j << 8);
                PROCB(a.x, bi + 0u) PROCB(a.y, bi + 1u)
                PROCB(a.z, bi + 2u) PROCB(a.w, bi + 3u)
            }
            PROCB(tvu, 3072u + (u32)lane)
#undef PROCB
        } else {
            degen = true;   // hi-lo==1 with >CAP duplicates of key 'lo'
        }
    }

    u32 TK = 0, CO = HW - 1u;
    if (degen) {
        // exact tie cutoff by index, reload-based (never on real data)
        TK = lo;
        const u32 rk = KSEL - chi;
        u32 lo3 = 0u, hi3 = HW - 1u;
        while (lo3 < hi3) {
            const u32 mid = (lo3 + hi3) >> 1;
            u32 c = 0;
#pragma unroll 1
            for (int j = 0; j < 12; ++j) {
                const uint4 a = xr[lane + (j << 6)];
                const u32 bi = (u32)(lane << 2) + (u32)(j << 8);
                c += (u32)__popcll(__ballot(((a.x & 0x7fffffffu) == TK) && (bi + 0u) <= mid));
                c += (u32)__popcll(__ballot(((a.y & 0x7fffffffu) == TK) && (bi + 1u) <= mid));
                c += (u32)__popcll(__ballot(((a.z & 0x7fffffffu) == TK) && (bi + 2u) <= mid));
                c += (u32)__popcll(__ballot(((a.w & 0x7fffffffu) == TK) && (bi + 3u) <= mid));
            }
            c += (u32)__popcll(__ballot(((tvu & 0x7fffffffu) == TK) && (3072u + (u32)lane) <= mid));
            if (c >= rk) hi3 = mid; else lo3 = mid + 1u;
        }
        CO = lo3;
    } else {
        // ---- finisher on the LDS list (wave-local, no barriers)
        const u32 rk = KSEL - chi;       // 1 <= rk <= Lc
        u32 kk[8];
#pragma unroll
        for (int j2 = 0; j2 < 8; ++j2) {
            const u32 s = (u32)lane + (u32)(j2 << 6);
            kk[j2] = (s < Lc) ? (Lk[s] & 0x7fffffffu) : 0u;  // pad 0: < any probe (probes >= 1)
        }
        u32 lo2 = lo, hi2 = hi;
        bool done = false;
        while (hi2 - lo2 > 1u) {
            const u32 mid = lo2 + ((hi2 - lo2) >> 1);
            u32 c = 0;
#pragma unroll
            for (int j2 = 0; j2 < 8; ++j2)
                c += (u32)__popcll(__ballot(kk[j2] >= mid));
            if (c == rk) {
                // exact hit: threshold = min candidate >= mid, keep all of them
                u32 mn = 0xffffffffu;
#pragma unroll
                for (int j2 = 0; j2 < 8; ++j2) {
                    const u32 t = (kk[j2] >= mid) ? kk[j2] : 0xffffffffu;
                    mn = mn < t ? mn : t;
                }
#pragma unroll
                for (int o = 32; o >= 1; o >>= 1) {
                    const u32 t = (u32)__shfl_xor((int)mn, o, 64);
                    mn = mn < t ? mn : t;
                }
                TK = mn; done = true; break;
            }
            if (c > rk) lo2 = mid; else hi2 = mid;
        }
        if (!done) {
            TK = lo2;
            u32 cgt = 0;
#pragma unroll
            for (int j2 = 0; j2 < 8; ++j2)
                cgt += (u32)__popcll(__ballot(kk[j2] > TK));
            const u32 r = rk - cgt;      // equals to keep, >= 1
            u64 eqm[8];
            u32 eqs = 0;
#pragma unroll
            for (int j2 = 0; j2 < 8; ++j2) {
                const u32 s = (u32)lane + (u32)(j2 << 6);
                eqm[j2] = __ballot(kk[j2] == TK && s < Lc);  // guard: TK may equal pad 0 in fallback
                eqs += (u32)__popcll(eqm[j2]);
            }
            if (r != eqs) {
                // cold tie path: r-th smallest index among equals (all in the list)
                u32 lo3 = 0u, hi3 = HW - 1u;
                while (lo3 < hi3) {
                    const u32 mid = (lo3 + hi3) >> 1;
                    u32 c = 0;
#pragma unroll
                    for (int j2 = 0; j2 < 8; ++j2) {
                        const u32 s = (u32)lane + (u32)(j2 << 6);
                        c += (u32)__popcll(eqm[j2] & __ballot(Li[s] <= mid));
                    }
                    if (c >= r) hi3 = mid; else lo3 = mid + 1u;
                }
                CO = lo3;
            }
        }
    }

    // ---- order provisional stores before overwrites (same-wave W->W hazard)
    asm volatile("s_waitcnt vmcnt(0)" ::: "memory");

    if (!fullrw) {
        // ---- hot path: scatter-fix the kept band elements (lines are L2-hot)
#pragma unroll
        for (int j2 = 0; j2 < 8; ++j2) {
            const u32 s = (u32)lane + (u32)(j2 << 6);
            if (s < Lc) {
                const u32 uv  = Lk[s];
                const u32 key = uv & 0x7fffffffu;
                const u32 ix  = Li[s];
                if (key > TK || (key == TK && ix <= CO))
                    orow[ix] = __uint_as_float(uv);
            }
        }
    } else {
        // ---- cold path: rewrite whole row with the exact predicate
#define KEEPU(U, IDX) ((((U) & 0x7fffffffu) > TK ||                            \
                        (((U) & 0x7fffffffu) == TK && (IDX) <= CO)) ? (U) : 0u)
#pragma unroll 1
        for (int j = 0; j < 12; ++j) {
            const uint4 a = xr[lane + (j << 6)];
            const u32 bi = (u32)(lane << 2) + (u32)(j << 8);
            uint4 o;
            o.x = KEEPU(a.x, bi + 0u);
            o.y = KEEPU(a.y, bi + 1u);
            o.z = KEEPU(a.z, bi + 2u);
            o.w = KEEPU(a.w, bi + 3u);
            orwu[lane + (j << 6)] = o;
        }
        orow[3072 + lane] = __uint_as_float(KEEPU(tvu, 3072u + (u32)lane));
#undef KEEPU
    }
}

extern "C" void kernel_launch(void* const* d_in, const int* in_sizes, int n_in,
                              void* d_out, int out_size, void* d_ws, size_t ws_size,
                              hipStream_t stream) {
    const float* x = (const float*)d_in[0];
    float* out = (float*)d_out;
    const int rows = in_sizes[0] / HW;       // 8192
    topk_mask_kernel<<<rows / 4, NT, 0, stream>>>(x, out);
}